// Round 1
// baseline (544.014 us; speedup 1.0000x reference)
//
#include <hip/hip_runtime.h>
#include <cstdint>

typedef unsigned short u16;
typedef unsigned int u32;
typedef __attribute__((ext_vector_type(8))) short bf16x8;
typedef __attribute__((ext_vector_type(4))) float f32x4;

typedef const u32 __attribute__((address_space(1)))* gp_t;
typedef u32 __attribute__((address_space(3)))* lp_t;

__device__ __forceinline__ u16 f2bf(float f) {
    union { float f; u32 u; } v; v.f = f;
    u32 r = v.u + 0x7FFFu + ((v.u >> 16) & 1u);   // RNE
    return (u16)(r >> 16);
}
__device__ __forceinline__ float bf2f(u16 h) {
    union { u32 u; float f; } v; v.u = ((u32)h) << 16;
    return v.f;
}

// ---------------- pack x (fp32 -> bf16), vectorized ----------------
__global__ void k_pack_x(const float* __restrict__ x, u16* __restrict__ xb, int n4) {
    int stride = gridDim.x * blockDim.x;
    for (int i = blockIdx.x * blockDim.x + threadIdx.x; i < n4; i += stride) {
        float4 v = ((const float4*)x)[i];
        ushort4 o;
        o.x = f2bf(v.x); o.y = f2bf(v.y); o.z = f2bf(v.z); o.w = f2bf(v.w);
        ((ushort4*)xb)[i] = o;
    }
}

// ---------------- transpose weight [1024][ncols] f32 -> [ncols][1024] bf16 ----
__global__ void k_transpose_w(const float* __restrict__ src, u16* __restrict__ dst, int ncols) {
    __shared__ float t[64][65];
    int ntn = ncols >> 6;
    int kb = (blockIdx.x / ntn) * 64;
    int nb = (blockIdx.x % ntn) * 64;
    for (int i = threadIdx.x; i < 4096; i += 256) {
        int r = i >> 6, c = i & 63;
        t[r][c] = src[(long)(kb + r) * ncols + nb + c];
    }
    __syncthreads();
    for (int i = threadIdx.x; i < 4096; i += 256) {
        int r = i >> 6, c = i & 63;
        dst[(long)(nb + r) * 1024 + kb + c] = f2bf(t[c][r]);
    }
}

// ---------------- main GEMM: C[128x128] = A[M,K] * Bt[N,K]^T ----------------
// EPI 0: qkv epilogue (q/k -> channel-major qkT, v -> token-major v_tm), bf16 out
// EPI 1: proj epilogue (+bias), fp32 out
template<int EPI>
__global__ __launch_bounds__(256) void k_gemm(
    const u16* __restrict__ A, const u16* __restrict__ Bt,
    int K, int nTilesN,
    u16* __restrict__ qkT, u16* __restrict__ v_tm,
    float* __restrict__ outp, const float* __restrict__ bias)
{
    __shared__ u16 lA[128 * 32];
    __shared__ u16 lB[128 * 32];
    __shared__ u16 lC[128 * 136];   // padded pitch 136 (272B, 16B-aligned rows)

    const int tid = threadIdx.x;
    const int wid = tid >> 6, lane = tid & 63;
    const int bn = blockIdx.x % nTilesN;
    const long bm = blockIdx.x / nTilesN;
    const long m0 = bm * 128;
    const int n0 = bn * 128;
    const int wr = wid >> 1, wc = wid & 1;

    f32x4 acc[4][4];
#pragma unroll
    for (int i = 0; i < 4; ++i)
#pragma unroll
        for (int j = 0; j < 4; ++j)
            acc[i][j] = (f32x4){0.f, 0.f, 0.f, 0.f};

    const int srow = lane >> 2;     // staging: 4 lanes (16B each) per 64B row
    const int sslot = lane & 3;
    const int fr = lane & 15;       // frag row/col within 16
    const int fslot = lane >> 4;    // frag 16B k-slot

    for (int kt = 0; kt < K; kt += 32) {
        __syncthreads();
#pragma unroll
        for (int i = 0; i < 2; ++i) {
            const int row = wid * 32 + i * 16 + srow;
            const int sl = (sslot ^ ((row >> 1) & 3)) << 3;   // pre-swizzled source k-offset
            const u16* ga = A + (m0 + row) * (long)K + kt + sl;
            const u16* gb = Bt + (long)(n0 + row) * K + kt + sl;
            __builtin_amdgcn_global_load_lds((gp_t)ga, (lp_t)(lA + (wid * 2 + i) * 512), 16, 0, 0);
            __builtin_amdgcn_global_load_lds((gp_t)gb, (lp_t)(lB + (wid * 2 + i) * 512), 16, 0, 0);
        }
        __syncthreads();
        bf16x8 af[4], bfr[4];
#pragma unroll
        for (int mi = 0; mi < 4; ++mi) {
            const int row = wr * 64 + mi * 16 + fr;
            af[mi] = *(const bf16x8*)(lA + row * 32 + ((fslot ^ ((row >> 1) & 3)) << 3));
        }
#pragma unroll
        for (int ni = 0; ni < 4; ++ni) {
            const int row = wc * 64 + ni * 16 + fr;
            bfr[ni] = *(const bf16x8*)(lB + row * 32 + ((fslot ^ ((row >> 1) & 3)) << 3));
        }
#pragma unroll
        for (int mi = 0; mi < 4; ++mi)
#pragma unroll
            for (int ni = 0; ni < 4; ++ni)
                acc[mi][ni] = __builtin_amdgcn_mfma_f32_16x16x32_bf16(af[mi], bfr[ni], acc[mi][ni], 0, 0, 0);
    }
    __syncthreads();

    if (EPI == 0) {
        const long b = m0 >> 12;             // 4096 tokens per batch
        const int tok0 = (int)(m0 & 4095);
        if (n0 < 2048) {
            // q/k: transpose tile in LDS -> lC[ch][tok]
#pragma unroll
            for (int mi = 0; mi < 4; ++mi)
#pragma unroll
                for (int ni = 0; ni < 4; ++ni) {
                    const int ch = wc * 64 + ni * 16 + fr;
                    const int tk = wr * 64 + mi * 16 + (fslot << 2);
                    ushort4 w;
                    w.x = f2bf(acc[mi][ni][0]); w.y = f2bf(acc[mi][ni][1]);
                    w.z = f2bf(acc[mi][ni][2]); w.w = f2bf(acc[mi][ni][3]);
                    *(ushort4*)(lC + ch * 136 + tk) = w;
                }
            __syncthreads();
            const int ch_i = tid >> 1, half = tid & 1;
            const u16* sp = lC + ch_i * 136 + half * 64;
            u16* dp = qkT + ((b * 2048 + n0 + ch_i) * 4096L + tok0 + half * 64);
#pragma unroll
            for (int i = 0; i < 8; ++i)
                ((uint4*)dp)[i] = ((const uint4*)sp)[i];
        } else {
            // v: token-major lC[tok][ch]
#pragma unroll
            for (int mi = 0; mi < 4; ++mi)
#pragma unroll
                for (int ni = 0; ni < 4; ++ni) {
                    const int ch = wc * 64 + ni * 16 + fr;
                    const int tk = wr * 64 + mi * 16 + (fslot << 2);
#pragma unroll
                    for (int r = 0; r < 4; ++r)
                        lC[(tk + r) * 136 + ch] = f2bf(acc[mi][ni][r]);
                }
            __syncthreads();
            const int tk_i = tid >> 1, half = tid & 1;
            const u16* sp = lC + tk_i * 136 + half * 64;
            u16* dp = v_tm + ((b * 4096 + tok0 + tk_i) * 1024L + (n0 - 2048) + half * 64);
#pragma unroll
            for (int i = 0; i < 8; ++i)
                ((uint4*)dp)[i] = ((const uint4*)sp)[i];
        }
    } else {
#pragma unroll
        for (int ni = 0; ni < 4; ++ni) {
            const int ch = n0 + wc * 64 + ni * 16 + fr;
            const float bi = bias[ch];
#pragma unroll
            for (int mi = 0; mi < 4; ++mi) {
                const long tok = m0 + wr * 64 + mi * 16 + (fslot << 2);
#pragma unroll
                for (int r = 0; r < 4; ++r)
                    outp[(tok + r) * 1024 + ch] = acc[mi][ni][r] + bi;
            }
        }
    }
}

// ---------------- per-channel 1/max(||row||,eps) over qkT rows ----------------
__global__ void k_norms(const u16* __restrict__ qkT, float* __restrict__ norms) {
    const int row = blockIdx.x * 4 + (threadIdx.x >> 6);   // [0, 16384)
    const int lane = threadIdx.x & 63;
    const u16* p = qkT + (long)row * 4096;
    float s = 0.f;
    for (int i = lane * 8; i < 4096; i += 512) {
        uint4 v = *(const uint4*)(p + i);
        float a, b2;
        a = bf2f((u16)(v.x & 0xFFFF)); b2 = bf2f((u16)(v.x >> 16)); s += a * a + b2 * b2;
        a = bf2f((u16)(v.y & 0xFFFF)); b2 = bf2f((u16)(v.y >> 16)); s += a * a + b2 * b2;
        a = bf2f((u16)(v.z & 0xFFFF)); b2 = bf2f((u16)(v.z >> 16)); s += a * a + b2 * b2;
        a = bf2f((u16)(v.w & 0xFFFF)); b2 = bf2f((u16)(v.w >> 16)); s += a * a + b2 * b2;
    }
#pragma unroll
    for (int off = 32; off > 0; off >>= 1) s += __shfl_down(s, off);
    if (lane == 0) norms[row] = 1.f / fmaxf(sqrtf(s), 1e-12f);
}

// ---------------- QK^T + scale + softmax per (b,h) ----------------
__global__ __launch_bounds__(256) void k_qk(
    const u16* __restrict__ qkT, const float* __restrict__ norms,
    const float* __restrict__ temperature, u16* __restrict__ attn_g)
{
    __shared__ u16 lQ[64 * 128];
    __shared__ u16 lK[64 * 128];
    __shared__ float lS[64 * 65];
    __shared__ float sKn[64];

    const int bh = blockIdx.x;
    const int b = bh >> 4, h = bh & 15;
    const int tid = threadIdx.x;
    const int wid = tid >> 6, lane = tid & 63;
    const int wr = wid >> 1, wc = wid & 1;
    const int fr = lane & 15;

    if (tid < 64) sKn[tid] = norms[b * 2048 + 1024 + h * 64 + tid];

    f32x4 acc[2][2];
#pragma unroll
    for (int i = 0; i < 2; ++i)
#pragma unroll
        for (int j = 0; j < 2; ++j) acc[i][j] = (f32x4){0.f, 0.f, 0.f, 0.f};

    const int srow4 = lane >> 4;     // staging: 16 lanes per 256B row
    const int sslot = lane & 15;

    for (int n0 = 0; n0 < 4096; n0 += 128) {
        __syncthreads();
#pragma unroll
        for (int i = 0; i < 8; ++i) {
            const int cc = wid * 8 + i;          // 32 calls: 16 q + 16 k
            const int mat = cc >> 4;
            const int row = (cc & 15) * 4 + srow4;
            const int col = n0 + ((sslot ^ (row & 7)) << 3);
            const u16* g = qkT + (((long)b * 2048 + mat * 1024 + h * 64 + row) * 4096 + col);
            u16* l = (mat ? lK : lQ) + (cc & 15) * 512;
            __builtin_amdgcn_global_load_lds((gp_t)g, (lp_t)l, 16, 0, 0);
        }
        __syncthreads();
#pragma unroll
        for (int s = 0; s < 4; ++s) {
            bf16x8 aq[2], bk[2];
#pragma unroll
            for (int mi = 0; mi < 2; ++mi) {
                const int rq_ = wr * 32 + mi * 16 + fr;
                aq[mi] = *(const bf16x8*)(lQ + rq_ * 128 + (((s * 4 + (lane >> 4)) ^ (rq_ & 7)) << 3));
                const int rk_ = wc * 32 + mi * 16 + fr;
                bk[mi] = *(const bf16x8*)(lK + rk_ * 128 + (((s * 4 + (lane >> 4)) ^ (rk_ & 7)) << 3));
            }
#pragma unroll
            for (int mi = 0; mi < 2; ++mi)
#pragma unroll
                for (int ni = 0; ni < 2; ++ni)
                    acc[mi][ni] = __builtin_amdgcn_mfma_f32_16x16x32_bf16(aq[mi], bk[ni], acc[mi][ni], 0, 0, 0);
        }
    }
#pragma unroll
    for (int mi = 0; mi < 2; ++mi)
#pragma unroll
        for (int ni = 0; ni < 2; ++ni) {
            const int d0 = wr * 32 + mi * 16 + ((lane >> 4) << 2);
            const int e = wc * 32 + ni * 16 + fr;
#pragma unroll
            for (int r = 0; r < 4; ++r)
                lS[(d0 + r) * 65 + e] = acc[mi][ni][r];
        }
    __syncthreads();
    if (tid < 64) {
        const int d = tid;
        const float rq = norms[b * 2048 + h * 64 + d];
        const float tmp = temperature[h];
        float mx = -1e30f;
        for (int e = 0; e < 64; ++e) {
            float v = lS[d * 65 + e] * rq * sKn[e] * tmp;
            lS[d * 65 + e] = v;
            mx = fmaxf(mx, v);
        }
        float sum = 0.f;
        for (int e = 0; e < 64; ++e) {
            float p = __expf(lS[d * 65 + e] - mx);
            lS[d * 65 + e] = p;
            sum += p;
        }
        const float inv = 1.f / sum;
        u16* dst = attn_g + ((long)bh * 64 + d) * 64;
        for (int e = 0; e < 64; ++e)
            dst[e] = f2bf(lS[d * 65 + e] * inv);
    }
}

// ---------------- PV: y[b, n, h*64+d] = sum_e attn[d][e] * v[e][n] ----------------
__global__ __launch_bounds__(256) void k_pv(
    const u16* __restrict__ attn_g, const u16* __restrict__ v_tm,
    u16* __restrict__ y)
{
    __shared__ u16 lP[64 * 72];     // attn bf16, pitch 72 (144B rows)
    __shared__ u16 lV[128 * 64];    // [tok][e], swizzled
    __shared__ u16 lY[128 * 72];    // [tok][d], pitch 72

    const int blk = blockIdx.x;     // bh*16 + seg
    const int seg = blk & 15, bh = blk >> 4;
    const int b = bh >> 4, h = bh & 15;
    const int tid = threadIdx.x;
    const int wid = tid >> 6, lane = tid & 63;
    const int wr = wid >> 1, wc = wid & 1;
    const int fr = lane & 15;

    {   // load attn tile -> lP
        const int d = tid >> 2, part = tid & 3;
        const u16* g = attn_g + ((long)bh * 64 + d) * 64 + part * 16;
        u16* l = lP + d * 72 + part * 16;
        *(uint4*)(l) = *(const uint4*)(g);
        *(uint4*)(l + 8) = *(const uint4*)(g + 8);
    }

    for (int cn = 0; cn < 2; ++cn) {
        const int tok0 = seg * 256 + cn * 128;
        __syncthreads();
#pragma unroll
        for (int i = 0; i < 4; ++i) {
            const int cc = wid * 4 + i;                 // 16 calls of 8 rows
            const int row = cc * 8 + (lane >> 3);
            const int slot = lane & 7;
            const u16* g = v_tm + ((long)(b * 4096 + tok0 + row)) * 1024 + h * 64 + ((slot ^ (row & 7)) << 3);
            __builtin_amdgcn_global_load_lds((gp_t)g, (lp_t)(lV + cc * 512), 16, 0, 0);
        }
        __syncthreads();
        f32x4 acc[2][4];
#pragma unroll
        for (int i = 0; i < 2; ++i)
#pragma unroll
            for (int j = 0; j < 4; ++j) acc[i][j] = (f32x4){0.f, 0.f, 0.f, 0.f};
#pragma unroll
        for (int s = 0; s < 2; ++s) {
            bf16x8 ap[2];
#pragma unroll
            for (int mi = 0; mi < 2; ++mi) {
                const int d = wr * 32 + mi * 16 + fr;
                ap[mi] = *(const bf16x8*)(lP + d * 72 + s * 32 + ((lane >> 4) << 3));
            }
#pragma unroll
            for (int ni = 0; ni < 4; ++ni) {
                const int tr = wc * 64 + ni * 16 + fr;
                const bf16x8 bv = *(const bf16x8*)(lV + tr * 64 + (((s * 4 + (lane >> 4)) ^ (tr & 7)) << 3));
#pragma unroll
                for (int mi = 0; mi < 2; ++mi)
                    acc[mi][ni] = __builtin_amdgcn_mfma_f32_16x16x32_bf16(ap[mi], bv, acc[mi][ni], 0, 0, 0);
            }
        }
#pragma unroll
        for (int mi = 0; mi < 2; ++mi)
#pragma unroll
            for (int ni = 0; ni < 4; ++ni) {
                const int tk = wc * 64 + ni * 16 + fr;
                const int d0 = wr * 32 + mi * 16 + ((lane >> 4) << 2);
                ushort4 w;
                w.x = f2bf(acc[mi][ni][0]); w.y = f2bf(acc[mi][ni][1]);
                w.z = f2bf(acc[mi][ni][2]); w.w = f2bf(acc[mi][ni][3]);
                *(ushort4*)(lY + tk * 72 + d0) = w;
            }
        __syncthreads();
        {
            const int tk = tid >> 1, half = tid & 1;
            const u16* sp = lY + tk * 72 + half * 32;
            u16* dp = y + ((long)(b * 4096 + tok0 + tk)) * 1024 + h * 64 + half * 32;
#pragma unroll
            for (int i = 0; i < 4; ++i)
                ((uint4*)dp)[i] = ((const uint4*)sp)[i];
        }
    }
}

// ---------------- launch ----------------
extern "C" void kernel_launch(void* const* d_in, const int* in_sizes, int n_in,
                              void* d_out, int out_size, void* d_ws, size_t ws_size,
                              hipStream_t stream) {
    const float* x = (const float*)d_in[0];
    const float* w_qkv = (const float*)d_in[1];
    const float* temperature = (const float*)d_in[2];
    const float* w_proj = (const float*)d_in[3];
    const float* b_proj = (const float*)d_in[4];
    float* out = (float*)d_out;
    char* ws = (char*)d_ws;

    u16* wqT   = (u16*)(ws);                       //   6,291,456 B  [3072][1024] bf16
    u16* wpT   = (u16*)(ws + 6291456);             //   2,097,152 B  [1024][1024] bf16
    u16* xb    = (u16*)(ws + 8388608);             //  67,108,864 B  [32768][1024] bf16
    u16* qkT   = (u16*)(ws + 75497472);            // 134,217,728 B  [8][2048][4096] bf16
    u16* v_tm  = (u16*)(ws + 209715200);           //  67,108,864 B  [8][4096][1024] bf16
    float* norms = (float*)(ws + 276824064);       //      65,536 B  [8][2048] f32
    u16* attn_g = (u16*)(ws + 276889600);          //   1,048,576 B  [128][64][64] bf16
    u16* y = xb;                                   // alias: xb dead after GEMM1

    k_pack_x<<<2048, 256, 0, stream>>>(x, xb, 8388608);
    k_transpose_w<<<768, 256, 0, stream>>>(w_qkv, wqT, 3072);
    k_transpose_w<<<256, 256, 0, stream>>>(w_proj, wpT, 1024);
    k_gemm<0><<<6144, 256, 0, stream>>>(xb, wqT, 1024, 24, qkT, v_tm, nullptr, nullptr);
    k_norms<<<4096, 256, 0, stream>>>(qkT, norms);
    k_qk<<<128, 256, 0, stream>>>(qkT, norms, temperature, attn_g);
    k_pv<<<2048, 256, 0, stream>>>(attn_g, v_tm, y);
    k_gemm<1><<<2048, 256, 0, stream>>>(y, wpT, 1024, 8, nullptr, nullptr, out, b_proj);
}

// Round 2
// 423.413 us; speedup vs baseline: 1.2848x; 1.2848x over previous
//
#include <hip/hip_runtime.h>
#include <cstdint>

typedef unsigned short u16;
typedef unsigned int u32;
typedef __attribute__((ext_vector_type(8))) short bf16x8;
typedef __attribute__((ext_vector_type(4))) float f32x4;

typedef const u32 __attribute__((address_space(1)))* gp_t;
typedef u32 __attribute__((address_space(3)))* lp_t;

__device__ __forceinline__ u16 f2bf(float f) {
    union { float f; u32 u; } v; v.f = f;
    u32 r = v.u + 0x7FFFu + ((v.u >> 16) & 1u);   // RNE
    return (u16)(r >> 16);
}
__device__ __forceinline__ float bf2f(u16 h) {
    union { u32 u; float f; } v; v.u = ((u32)h) << 16;
    return v.f;
}

// ---------------- pack x (fp32 -> bf16), vectorized ----------------
__global__ void k_pack_x(const float* __restrict__ x, u16* __restrict__ xb, int n4) {
    int stride = gridDim.x * blockDim.x;
    for (int i = blockIdx.x * blockDim.x + threadIdx.x; i < n4; i += stride) {
        float4 v = ((const float4*)x)[i];
        ushort4 o;
        o.x = f2bf(v.x); o.y = f2bf(v.y); o.z = f2bf(v.z); o.w = f2bf(v.w);
        ((ushort4*)xb)[i] = o;
    }
}

// ---------------- transpose weight [1024][ncols] f32 -> [ncols][1024] bf16 ----
__global__ void k_transpose_w(const float* __restrict__ src, u16* __restrict__ dst, int ncols) {
    __shared__ float t[64][65];
    int ntn = ncols >> 6;
    int kb = (blockIdx.x / ntn) * 64;
    int nb = (blockIdx.x % ntn) * 64;
    for (int i = threadIdx.x; i < 4096; i += 256) {
        int r = i >> 6, c = i & 63;
        t[r][c] = src[(long)(kb + r) * ncols + nb + c];
    }
    __syncthreads();
    for (int i = threadIdx.x; i < 4096; i += 256) {
        int r = i >> 6, c = i & 63;
        dst[(long)(nb + r) * 1024 + kb + c] = f2bf(t[c][r]);
    }
}

// ---------------- 256x256 8-phase-style GEMM, BK=32, K=1024 fixed ----------------
// C[256x256] = A[M,1024] * Bt[N,1024]^T
// EPI 0: qkv epilogue (q/k -> channel-major qkT, v -> token-major v_tm), bf16 out
// EPI 1: proj epilogue (+bias), fp32 out
template<int EPI>
__global__ __launch_bounds__(512, 2) void k_gemm(
    const u16* __restrict__ A, const u16* __restrict__ Bt,
    int nTilesN,
    u16* __restrict__ qkT, u16* __restrict__ v_tm,
    float* __restrict__ outp, const float* __restrict__ bias)
{
    __shared__ uint4 smem4[8704];            // 139264 B (main loop uses first 128 KiB)
    u16* sm = (u16*)smem4;

    const int tid = threadIdx.x;
    const int wid = tid >> 6, lane = tid & 63;
    const int wr = wid >> 2, wc = wid & 3;   // 2M x 4N waves
    const int fr = lane & 15, sl = lane >> 4;

    // XCD-aware bijective swizzle (grid % 8 == 0 for both GEMMs)
    const int nwg = gridDim.x;
    const int cpx = nwg >> 3;
    const int logical = (blockIdx.x & 7) * cpx + (blockIdx.x >> 3);
    const int bn = logical % nTilesN;
    const long bm = logical / nTilesN;
    const long m0 = bm * 256;
    const int n0 = bn * 256;
    const int K = 1024;

    // staging lane geometry: chunk = 16 rows x 64B, lane covers row lane>>2, slot lane&3
    const int srow = lane >> 2;
    const int sslot = lane & 3;
    const int rA0 = wid * 32 + srow;         // chunk c0 = wid*2 rows
    const int rA1 = rA0 + 16;                // chunk c1
    const u16* pA0 = A + (m0 + rA0) * (long)K + ((sslot ^ ((rA0 >> 1) & 3)) << 3);
    const u16* pA1 = A + (m0 + rA1) * (long)K + ((sslot ^ ((rA1 >> 1) & 3)) << 3);
    const u16* pB0 = Bt + (long)(n0 + rA0) * K + ((sslot ^ ((rA0 >> 1) & 3)) << 3);
    const u16* pB1 = Bt + (long)(n0 + rA1) * K + ((sslot ^ ((rA1 >> 1) & 3)) << 3);
    const int cA0 = wid * 1024;              // elems: chunk (wid*2)*512
    const int cA1 = cA0 + 512;

    f32x4 acc[8][4];
#pragma unroll
    for (int i = 0; i < 8; ++i)
#pragma unroll
        for (int j = 0; j < 4; ++j) acc[i][j] = (f32x4){0.f, 0.f, 0.f, 0.f};

    // prologue: stage K-tiles 0..2 (12 wave-loads)
#pragma unroll
    for (int t = 0; t < 3; ++t) {
        const int sb = t * 16384;
        __builtin_amdgcn_global_load_lds((gp_t)(pA0 + t * 32), (lp_t)(sm + sb + cA0), 16, 0, 0);
        __builtin_amdgcn_global_load_lds((gp_t)(pA1 + t * 32), (lp_t)(sm + sb + cA1), 16, 0, 0);
        __builtin_amdgcn_global_load_lds((gp_t)(pB0 + t * 32), (lp_t)(sm + sb + 8192 + cA0), 16, 0, 0);
        __builtin_amdgcn_global_load_lds((gp_t)(pB1 + t * 32), (lp_t)(sm + sb + 8192 + cA1), 16, 0, 0);
    }
    asm volatile("s_waitcnt vmcnt(8)" ::: "memory");   // K-tile 0 landed
    __builtin_amdgcn_s_barrier();

#pragma unroll 4
    for (int t = 0; t < 32; ++t) {
        const int cur = t & 3;
        const u16* bufA = sm + cur * 16384;
        const u16* bufB = bufA + 8192;
        const int tt = (t + 3) & 31;          // wrap staging: uniform vmcnt, harmless reloads
        const int sb = (tt & 3) * 16384;

        bf16x8 bfr[4], af[4];
        // ---- phase 0: B frags + A frags (mi 0..3), stage A chunks of tile tt ----
#pragma unroll
        for (int ni = 0; ni < 4; ++ni) {
            const int r = wc * 64 + ni * 16 + fr;
            bfr[ni] = *(const bf16x8*)(bufB + r * 32 + ((sl ^ ((r >> 1) & 3)) << 3));
        }
#pragma unroll
        for (int mi = 0; mi < 4; ++mi) {
            const int r = wr * 128 + mi * 16 + fr;
            af[mi] = *(const bf16x8*)(bufA + r * 32 + ((sl ^ ((r >> 1) & 3)) << 3));
        }
        __builtin_amdgcn_global_load_lds((gp_t)(pA0 + tt * 32), (lp_t)(sm + sb + cA0), 16, 0, 0);
        __builtin_amdgcn_global_load_lds((gp_t)(pA1 + tt * 32), (lp_t)(sm + sb + cA1), 16, 0, 0);
        __builtin_amdgcn_s_barrier();
        __builtin_amdgcn_s_setprio(1);
#pragma unroll
        for (int mi = 0; mi < 4; ++mi)
#pragma unroll
            for (int ni = 0; ni < 4; ++ni)
                acc[mi][ni] = __builtin_amdgcn_mfma_f32_16x16x32_bf16(af[mi], bfr[ni], acc[mi][ni], 0, 0, 0);
        __builtin_amdgcn_s_setprio(0);
        __builtin_amdgcn_s_barrier();

        // ---- phase 1: A frags (mi 4..7), stage B chunks of tile tt, counted wait ----
#pragma unroll
        for (int mi = 0; mi < 4; ++mi) {
            const int r = wr * 128 + (mi + 4) * 16 + fr;
            af[mi] = *(const bf16x8*)(bufA + r * 32 + ((sl ^ ((r >> 1) & 3)) << 3));
        }
        __builtin_amdgcn_global_load_lds((gp_t)(pB0 + tt * 32), (lp_t)(sm + sb + 8192 + cA0), 16, 0, 0);
        __builtin_amdgcn_global_load_lds((gp_t)(pB1 + tt * 32), (lp_t)(sm + sb + 8192 + cA1), 16, 0, 0);
        asm volatile("s_waitcnt vmcnt(8)" ::: "memory");   // tile t+1 fully landed (12 out -> 8)
        __builtin_amdgcn_s_barrier();
        __builtin_amdgcn_s_setprio(1);
#pragma unroll
        for (int mi = 0; mi < 4; ++mi)
#pragma unroll
            for (int ni = 0; ni < 4; ++ni)
                acc[mi + 4][ni] = __builtin_amdgcn_mfma_f32_16x16x32_bf16(af[mi], bfr[ni], acc[mi + 4][ni], 0, 0, 0);
        __builtin_amdgcn_s_setprio(0);
        __builtin_amdgcn_s_barrier();
    }
    asm volatile("s_waitcnt vmcnt(0)" ::: "memory");   // drain stray wrap loads before aliasing smem
    __syncthreads();

    if (EPI == 0) {
        const long b = m0 >> 12;
        const int tok0 = (int)(m0 & 4095);
        if (n0 < 2048) {
            // q/k: per-wave transpose piece [64 ch][pitch 136 tok] bf16
            u16* piece = sm + wid * 8704;
#pragma unroll
            for (int mi = 0; mi < 8; ++mi)
#pragma unroll
                for (int ni = 0; ni < 4; ++ni) {
                    const int ch = ni * 16 + fr;
                    const int tk = mi * 16 + sl * 4;
                    ushort4 w;
                    w.x = f2bf(acc[mi][ni][0]); w.y = f2bf(acc[mi][ni][1]);
                    w.z = f2bf(acc[mi][ni][2]); w.w = f2bf(acc[mi][ni][3]);
                    *(ushort4*)(piece + ch * 136 + tk) = w;
                }
            __syncthreads();
            // 512 rows (8 pieces x 64 ch) x 256B, 16B chunks, 16-lane row bursts
#pragma unroll
            for (int i = 0; i < 16; ++i) {
                const int chunk = i * 512 + tid;
                const int row = chunk >> 4, c16 = chunk & 15;
                const int p = row >> 6, chl = row & 63;
                const int wrp = p >> 2, wcp = p & 3;
                const uint4 v = *(const uint4*)(sm + p * 8704 + chl * 136 + c16 * 8);
                *(uint4*)(qkT + ((b * 2048 + n0 + wcp * 64 + chl) * 4096L + tok0 + wrp * 128 + c16 * 8)) = v;
            }
        } else {
            // v: per-wave piece [128 tok][pitch 68 ch] bf16
            u16* piece = sm + wid * 8704;
#pragma unroll
            for (int mi = 0; mi < 8; ++mi)
#pragma unroll
                for (int ni = 0; ni < 4; ++ni) {
                    const int ch = ni * 16 + fr;
                    const int tk = mi * 16 + sl * 4;
#pragma unroll
                    for (int r = 0; r < 4; ++r)
                        piece[(tk + r) * 68 + ch] = f2bf(acc[mi][ni][r]);
                }
            __syncthreads();
            // 1024 rows (8 pieces x 128 tok) x 128B, 8B chunks, 16-lane row bursts
#pragma unroll
            for (int i = 0; i < 32; ++i) {
                const int chunk = i * 512 + tid;
                const int row = chunk >> 4, c8 = chunk & 15;
                const int p = row >> 7, tk = row & 127;
                const int wrp = p >> 2, wcp = p & 3;
                const uint2 v = *(const uint2*)(sm + p * 8704 + tk * 68 + c8 * 4);
                *(uint2*)(v_tm + ((b * 4096 + tok0 + wrp * 128 + tk) * 1024L + (n0 - 2048) + wcp * 64 + c8 * 4)) = v;
            }
        }
    } else {
        float bi[4];
#pragma unroll
        for (int ni = 0; ni < 4; ++ni) bi[ni] = bias[n0 + wc * 64 + ni * 16 + fr];
        float* pieceF = (float*)smem4 + wid * 4352;   // [64 tok][pitch 68 ch] f32
#pragma unroll
        for (int pass = 0; pass < 2; ++pass) {
            if (pass) __syncthreads();
#pragma unroll
            for (int mi2 = 0; mi2 < 4; ++mi2) {
                const int mi = pass * 4 + mi2;
#pragma unroll
                for (int ni = 0; ni < 4; ++ni) {
                    const int ch = ni * 16 + fr;
                    const int tk = mi2 * 16 + sl * 4;
#pragma unroll
                    for (int r = 0; r < 4; ++r)
                        pieceF[(tk + r) * 68 + ch] = acc[mi][ni][r] + bi[ni];
                }
            }
            __syncthreads();
#pragma unroll
            for (int i = 0; i < 16; ++i) {
                const int chunk = i * 512 + tid;
                const int row = chunk >> 4, c4 = chunk & 15;
                const int p = row >> 6, tk = row & 63;
                const int wrp = p >> 2, wcp = p & 3;
                const float4 v = *(const float4*)((float*)smem4 + p * 4352 + tk * 68 + c4 * 4);
                *(float4*)(outp + (m0 + wrp * 128 + pass * 64 + tk) * 1024L + n0 + wcp * 64 + c4 * 4) = v;
            }
        }
    }
}

// ---------------- per-channel 1/max(||row||,eps) over qkT rows ----------------
__global__ void k_norms(const u16* __restrict__ qkT, float* __restrict__ norms) {
    const int row = blockIdx.x * 4 + (threadIdx.x >> 6);   // [0, 16384)
    const int lane = threadIdx.x & 63;
    const u16* p = qkT + (long)row * 4096;
    float s = 0.f;
    for (int i = lane * 8; i < 4096; i += 512) {
        uint4 v = *(const uint4*)(p + i);
        float a, b2;
        a = bf2f((u16)(v.x & 0xFFFF)); b2 = bf2f((u16)(v.x >> 16)); s += a * a + b2 * b2;
        a = bf2f((u16)(v.y & 0xFFFF)); b2 = bf2f((u16)(v.y >> 16)); s += a * a + b2 * b2;
        a = bf2f((u16)(v.z & 0xFFFF)); b2 = bf2f((u16)(v.z >> 16)); s += a * a + b2 * b2;
        a = bf2f((u16)(v.w & 0xFFFF)); b2 = bf2f((u16)(v.w >> 16)); s += a * a + b2 * b2;
    }
#pragma unroll
    for (int off = 32; off > 0; off >>= 1) s += __shfl_down(s, off);
    if (lane == 0) norms[row] = 1.f / fmaxf(sqrtf(s), 1e-12f);
}

// ---------------- QK^T + scale + softmax per (b,h) ----------------
__global__ __launch_bounds__(256) void k_qk(
    const u16* __restrict__ qkT, const float* __restrict__ norms,
    const float* __restrict__ temperature, u16* __restrict__ attn_g)
{
    __shared__ u16 lQ[64 * 128];
    __shared__ u16 lK[64 * 128];
    __shared__ float lS[64 * 65];
    __shared__ float sKn[64];

    const int bh = blockIdx.x;
    const int b = bh >> 4, h = bh & 15;
    const int tid = threadIdx.x;
    const int wid = tid >> 6, lane = tid & 63;
    const int wr = wid >> 1, wc = wid & 1;
    const int fr = lane & 15;

    if (tid < 64) sKn[tid] = norms[b * 2048 + 1024 + h * 64 + tid];

    f32x4 acc[2][2];
#pragma unroll
    for (int i = 0; i < 2; ++i)
#pragma unroll
        for (int j = 0; j < 2; ++j) acc[i][j] = (f32x4){0.f, 0.f, 0.f, 0.f};

    const int srow4 = lane >> 4;
    const int sslot = lane & 15;

    for (int n0 = 0; n0 < 4096; n0 += 128) {
        __syncthreads();
#pragma unroll
        for (int i = 0; i < 8; ++i) {
            const int cc = wid * 8 + i;
            const int mat = cc >> 4;
            const int row = (cc & 15) * 4 + srow4;
            const int col = n0 + ((sslot ^ (row & 7)) << 3);
            const u16* g = qkT + (((long)b * 2048 + mat * 1024 + h * 64 + row) * 4096 + col);
            u16* l = (mat ? lK : lQ) + (cc & 15) * 512;
            __builtin_amdgcn_global_load_lds((gp_t)g, (lp_t)l, 16, 0, 0);
        }
        __syncthreads();
#pragma unroll
        for (int s = 0; s < 4; ++s) {
            bf16x8 aq[2], bk[2];
#pragma unroll
            for (int mi = 0; mi < 2; ++mi) {
                const int rq_ = wr * 32 + mi * 16 + fr;
                aq[mi] = *(const bf16x8*)(lQ + rq_ * 128 + (((s * 4 + (lane >> 4)) ^ (rq_ & 7)) << 3));
                const int rk_ = wc * 32 + mi * 16 + fr;
                bk[mi] = *(const bf16x8*)(lK + rk_ * 128 + (((s * 4 + (lane >> 4)) ^ (rk_ & 7)) << 3));
            }
#pragma unroll
            for (int mi = 0; mi < 2; ++mi)
#pragma unroll
                for (int ni = 0; ni < 2; ++ni)
                    acc[mi][ni] = __builtin_amdgcn_mfma_f32_16x16x32_bf16(aq[mi], bk[ni], acc[mi][ni], 0, 0, 0);
        }
    }
#pragma unroll
    for (int mi = 0; mi < 2; ++mi)
#pragma unroll
        for (int ni = 0; ni < 2; ++ni) {
            const int d0 = wr * 32 + mi * 16 + ((lane >> 4) << 2);
            const int e = wc * 32 + ni * 16 + fr;
#pragma unroll
            for (int r = 0; r < 4; ++r)
                lS[(d0 + r) * 65 + e] = acc[mi][ni][r];
        }
    __syncthreads();
    if (tid < 64) {
        const int d = tid;
        const float rq = norms[b * 2048 + h * 64 + d];
        const float tmp = temperature[h];
        float mx = -1e30f;
        for (int e = 0; e < 64; ++e) {
            float v = lS[d * 65 + e] * rq * sKn[e] * tmp;
            lS[d * 65 + e] = v;
            mx = fmaxf(mx, v);
        }
        float sum = 0.f;
        for (int e = 0; e < 64; ++e) {
            float p = __expf(lS[d * 65 + e] - mx);
            lS[d * 65 + e] = p;
            sum += p;
        }
        const float inv = 1.f / sum;
        u16* dst = attn_g + ((long)bh * 64 + d) * 64;
        for (int e = 0; e < 64; ++e)
            dst[e] = f2bf(lS[d * 65 + e] * inv);
    }
}

// ---------------- PV: y[b, n, h*64+d] = sum_e attn[d][e] * v[e][n] ----------------
__global__ __launch_bounds__(256) void k_pv(
    const u16* __restrict__ attn_g, const u16* __restrict__ v_tm,
    u16* __restrict__ y)
{
    __shared__ u16 lP[64 * 72];
    __shared__ u16 lV[128 * 64];
    __shared__ u16 lY[128 * 72];

    const int blk = blockIdx.x;
    const int seg = blk & 15, bh = blk >> 4;
    const int b = bh >> 4, h = bh & 15;
    const int tid = threadIdx.x;
    const int wid = tid >> 6, lane = tid & 63;
    const int wr = wid >> 1, wc = wid & 1;
    const int fr = lane & 15;

    {
        const int d = tid >> 2, part = tid & 3;
        const u16* g = attn_g + ((long)bh * 64 + d) * 64 + part * 16;
        u16* l = lP + d * 72 + part * 16;
        *(uint4*)(l) = *(const uint4*)(g);
        *(uint4*)(l + 8) = *(const uint4*)(g + 8);
    }

    for (int cn = 0; cn < 2; ++cn) {
        const int tok0 = seg * 256 + cn * 128;
        __syncthreads();
#pragma unroll
        for (int i = 0; i < 4; ++i) {
            const int cc = wid * 4 + i;
            const int row = cc * 8 + (lane >> 3);
            const int slot = lane & 7;
            const u16* g = v_tm + ((long)(b * 4096 + tok0 + row)) * 1024 + h * 64 + ((slot ^ (row & 7)) << 3);
            __builtin_amdgcn_global_load_lds((gp_t)g, (lp_t)(lV + cc * 512), 16, 0, 0);
        }
        __syncthreads();
        f32x4 acc[2][4];
#pragma unroll
        for (int i = 0; i < 2; ++i)
#pragma unroll
            for (int j = 0; j < 4; ++j) acc[i][j] = (f32x4){0.f, 0.f, 0.f, 0.f};
#pragma unroll
        for (int s = 0; s < 2; ++s) {
            bf16x8 ap[2];
#pragma unroll
            for (int mi = 0; mi < 2; ++mi) {
                const int d = wr * 32 + mi * 16 + fr;
                ap[mi] = *(const bf16x8*)(lP + d * 72 + s * 32 + ((lane >> 4) << 3));
            }
#pragma unroll
            for (int ni = 0; ni < 4; ++ni) {
                const int tr = wc * 64 + ni * 16 + fr;
                const bf16x8 bv = *(const bf16x8*)(lV + tr * 64 + (((s * 4 + (lane >> 4)) ^ (tr & 7)) << 3));
#pragma unroll
                for (int mi = 0; mi < 2; ++mi)
                    acc[mi][ni] = __builtin_amdgcn_mfma_f32_16x16x32_bf16(ap[mi], bv, acc[mi][ni], 0, 0, 0);
            }
        }
#pragma unroll
        for (int mi = 0; mi < 2; ++mi)
#pragma unroll
            for (int ni = 0; ni < 4; ++ni) {
                const int tk = wc * 64 + ni * 16 + fr;
                const int d0 = wr * 32 + mi * 16 + ((lane >> 4) << 2);
                ushort4 w;
                w.x = f2bf(acc[mi][ni][0]); w.y = f2bf(acc[mi][ni][1]);
                w.z = f2bf(acc[mi][ni][2]); w.w = f2bf(acc[mi][ni][3]);
                *(ushort4*)(lY + tk * 72 + d0) = w;
            }
        __syncthreads();
        {
            const int tk = tid >> 1, half = tid & 1;
            const u16* sp = lY + tk * 72 + half * 32;
            u16* dp = y + ((long)(b * 4096 + tok0 + tk)) * 1024 + h * 64 + half * 32;
#pragma unroll
            for (int i = 0; i < 4; ++i)
                ((uint4*)dp)[i] = ((const uint4*)sp)[i];
        }
    }
}

// ---------------- launch ----------------
extern "C" void kernel_launch(void* const* d_in, const int* in_sizes, int n_in,
                              void* d_out, int out_size, void* d_ws, size_t ws_size,
                              hipStream_t stream) {
    const float* x = (const float*)d_in[0];
    const float* w_qkv = (const float*)d_in[1];
    const float* temperature = (const float*)d_in[2];
    const float* w_proj = (const float*)d_in[3];
    const float* b_proj = (const float*)d_in[4];
    float* out = (float*)d_out;
    char* ws = (char*)d_ws;

    u16* wqT   = (u16*)(ws);                       //   6,291,456 B  [3072][1024] bf16
    u16* wpT   = (u16*)(ws + 6291456);             //   2,097,152 B  [1024][1024] bf16
    u16* xb    = (u16*)(ws + 8388608);             //  67,108,864 B  [32768][1024] bf16
    u16* qkT   = (u16*)(ws + 75497472);            // 134,217,728 B  [8][2048][4096] bf16
    u16* v_tm  = (u16*)(ws + 209715200);           //  67,108,864 B  [8][4096][1024] bf16
    float* norms = (float*)(ws + 276824064);       //      65,536 B  [8][2048] f32
    u16* attn_g = (u16*)(ws + 276889600);          //   1,048,576 B  [128][64][64] bf16
    u16* y = xb;                                   // alias: xb dead after GEMM1

    k_pack_x<<<2048, 256, 0, stream>>>(x, xb, 8388608);
    k_transpose_w<<<768, 256, 0, stream>>>(w_qkv, wqT, 3072);
    k_transpose_w<<<256, 256, 0, stream>>>(w_proj, wpT, 1024);
    k_gemm<0><<<1536, 512, 0, stream>>>(xb, wqT, 12, qkT, v_tm, nullptr, nullptr);
    k_norms<<<4096, 256, 0, stream>>>(qkT, norms);
    k_qk<<<128, 256, 0, stream>>>(qkT, norms, temperature, attn_g);
    k_pv<<<2048, 256, 0, stream>>>(attn_g, v_tm, y);
    k_gemm<1><<<512, 512, 0, stream>>>(y, wpT, 4, nullptr, nullptr, out, b_proj);
}

// Round 3
// 416.636 us; speedup vs baseline: 1.3057x; 1.0163x over previous
//
#include <hip/hip_runtime.h>
#include <cstdint>

typedef unsigned short u16;
typedef unsigned int u32;
typedef __attribute__((ext_vector_type(8))) short bf16x8;
typedef __attribute__((ext_vector_type(4))) float f32x4;

typedef const u32 __attribute__((address_space(1)))* gp_t;
typedef u32 __attribute__((address_space(3)))* lp_t;

__device__ __forceinline__ u16 f2bf(float f) {
    union { float f; u32 u; } v; v.f = f;
    u32 r = v.u + 0x7FFFu + ((v.u >> 16) & 1u);   // RNE
    return (u16)(r >> 16);
}
__device__ __forceinline__ float bf2f(u16 h) {
    union { u32 u; float f; } v; v.u = ((u32)h) << 16;
    return v.f;
}

// ---------------- pack x (fp32 -> bf16), vectorized ----------------
__global__ void k_pack_x(const float* __restrict__ x, u16* __restrict__ xb, int n4) {
    int stride = gridDim.x * blockDim.x;
    for (int i = blockIdx.x * blockDim.x + threadIdx.x; i < n4; i += stride) {
        float4 v = ((const float4*)x)[i];
        ushort4 o;
        o.x = f2bf(v.x); o.y = f2bf(v.y); o.z = f2bf(v.z); o.w = f2bf(v.w);
        ((ushort4*)xb)[i] = o;
    }
}

// ---------------- transpose weight [1024][ncols] f32 -> [ncols][1024] bf16 ----
__global__ void k_transpose_w(const float* __restrict__ src, u16* __restrict__ dst, int ncols) {
    __shared__ float t[64][65];
    int ntn = ncols >> 6;
    int kb = (blockIdx.x / ntn) * 64;
    int nb = (blockIdx.x % ntn) * 64;
    for (int i = threadIdx.x; i < 4096; i += 256) {
        int r = i >> 6, c = i & 63;
        t[r][c] = src[(long)(kb + r) * ncols + nb + c];
    }
    __syncthreads();
    for (int i = threadIdx.x; i < 4096; i += 256) {
        int r = i >> 6, c = i & 63;
        dst[(long)(nb + r) * 1024 + kb + c] = f2bf(t[c][r]);
    }
}

// ---------------- 256x256 GEMM, BK=32, K=1024 fixed ----------------
template<int EPI>
__global__ __launch_bounds__(512, 2) void k_gemm(
    const u16* __restrict__ A, const u16* __restrict__ Bt,
    int nTilesN,
    u16* __restrict__ qkT, u16* __restrict__ v_tm,
    float* __restrict__ outp, const float* __restrict__ bias)
{
    __shared__ uint4 smem4[8704];            // 139264 B (main loop uses first 128 KiB)
    u16* sm = (u16*)smem4;

    const int tid = threadIdx.x;
    const int wid = tid >> 6, lane = tid & 63;
    const int wr = wid >> 2, wc = wid & 3;   // 2M x 4N waves
    const int fr = lane & 15, sl = lane >> 4;

    const int nwg = gridDim.x;
    const int cpx = nwg >> 3;
    const int logical = (blockIdx.x & 7) * cpx + (blockIdx.x >> 3);
    const int bn = logical % nTilesN;
    const long bm = logical / nTilesN;
    const long m0 = bm * 256;
    const int n0 = bn * 256;
    const int K = 1024;

    const int srow = lane >> 2;
    const int sslot = lane & 3;
    const int rA0 = wid * 32 + srow;
    const int rA1 = rA0 + 16;
    const u16* pA0 = A + (m0 + rA0) * (long)K + ((sslot ^ ((rA0 >> 1) & 3)) << 3);
    const u16* pA1 = A + (m0 + rA1) * (long)K + ((sslot ^ ((rA1 >> 1) & 3)) << 3);
    const u16* pB0 = Bt + (long)(n0 + rA0) * K + ((sslot ^ ((rA0 >> 1) & 3)) << 3);
    const u16* pB1 = Bt + (long)(n0 + rA1) * K + ((sslot ^ ((rA1 >> 1) & 3)) << 3);
    const int cA0 = wid * 1024;
    const int cA1 = cA0 + 512;

    f32x4 acc[8][4];
#pragma unroll
    for (int i = 0; i < 8; ++i)
#pragma unroll
        for (int j = 0; j < 4; ++j) acc[i][j] = (f32x4){0.f, 0.f, 0.f, 0.f};

#pragma unroll
    for (int t = 0; t < 3; ++t) {
        const int sb = t * 16384;
        __builtin_amdgcn_global_load_lds((gp_t)(pA0 + t * 32), (lp_t)(sm + sb + cA0), 16, 0, 0);
        __builtin_amdgcn_global_load_lds((gp_t)(pA1 + t * 32), (lp_t)(sm + sb + cA1), 16, 0, 0);
        __builtin_amdgcn_global_load_lds((gp_t)(pB0 + t * 32), (lp_t)(sm + sb + 8192 + cA0), 16, 0, 0);
        __builtin_amdgcn_global_load_lds((gp_t)(pB1 + t * 32), (lp_t)(sm + sb + 8192 + cA1), 16, 0, 0);
    }
    asm volatile("s_waitcnt vmcnt(8)" ::: "memory");
    __builtin_amdgcn_s_barrier();

#pragma unroll 4
    for (int t = 0; t < 32; ++t) {
        const int cur = t & 3;
        const u16* bufA = sm + cur * 16384;
        const u16* bufB = bufA + 8192;
        const int tt = (t + 3) & 31;
        const int sb = (tt & 3) * 16384;

        bf16x8 bfr[4], af[4];
#pragma unroll
        for (int ni = 0; ni < 4; ++ni) {
            const int r = wc * 64 + ni * 16 + fr;
            bfr[ni] = *(const bf16x8*)(bufB + r * 32 + ((sl ^ ((r >> 1) & 3)) << 3));
        }
#pragma unroll
        for (int mi = 0; mi < 4; ++mi) {
            const int r = wr * 128 + mi * 16 + fr;
            af[mi] = *(const bf16x8*)(bufA + r * 32 + ((sl ^ ((r >> 1) & 3)) << 3));
        }
        __builtin_amdgcn_global_load_lds((gp_t)(pA0 + tt * 32), (lp_t)(sm + sb + cA0), 16, 0, 0);
        __builtin_amdgcn_global_load_lds((gp_t)(pA1 + tt * 32), (lp_t)(sm + sb + cA1), 16, 0, 0);
        __builtin_amdgcn_s_barrier();
        __builtin_amdgcn_s_setprio(1);
#pragma unroll
        for (int mi = 0; mi < 4; ++mi)
#pragma unroll
            for (int ni = 0; ni < 4; ++ni)
                acc[mi][ni] = __builtin_amdgcn_mfma_f32_16x16x32_bf16(af[mi], bfr[ni], acc[mi][ni], 0, 0, 0);
        __builtin_amdgcn_s_setprio(0);
        __builtin_amdgcn_s_barrier();

#pragma unroll
        for (int mi = 0; mi < 4; ++mi) {
            const int r = wr * 128 + (mi + 4) * 16 + fr;
            af[mi] = *(const bf16x8*)(bufA + r * 32 + ((sl ^ ((r >> 1) & 3)) << 3));
        }
        __builtin_amdgcn_global_load_lds((gp_t)(pB0 + tt * 32), (lp_t)(sm + sb + 8192 + cA0), 16, 0, 0);
        __builtin_amdgcn_global_load_lds((gp_t)(pB1 + tt * 32), (lp_t)(sm + sb + 8192 + cA1), 16, 0, 0);
        asm volatile("s_waitcnt vmcnt(8)" ::: "memory");
        __builtin_amdgcn_s_barrier();
        __builtin_amdgcn_s_setprio(1);
#pragma unroll
        for (int mi = 0; mi < 4; ++mi)
#pragma unroll
            for (int ni = 0; ni < 4; ++ni)
                acc[mi + 4][ni] = __builtin_amdgcn_mfma_f32_16x16x32_bf16(af[mi], bfr[ni], acc[mi + 4][ni], 0, 0, 0);
        __builtin_amdgcn_s_setprio(0);
        __builtin_amdgcn_s_barrier();
    }
    asm volatile("s_waitcnt vmcnt(0)" ::: "memory");
    __syncthreads();

    if (EPI == 0) {
        const long b = m0 >> 12;
        const int tok0 = (int)(m0 & 4095);
        if (n0 < 2048) {
            u16* piece = sm + wid * 8704;
#pragma unroll
            for (int mi = 0; mi < 8; ++mi)
#pragma unroll
                for (int ni = 0; ni < 4; ++ni) {
                    const int ch = ni * 16 + fr;
                    const int tk = mi * 16 + sl * 4;
                    ushort4 w;
                    w.x = f2bf(acc[mi][ni][0]); w.y = f2bf(acc[mi][ni][1]);
                    w.z = f2bf(acc[mi][ni][2]); w.w = f2bf(acc[mi][ni][3]);
                    *(ushort4*)(piece + ch * 136 + tk) = w;
                }
            __syncthreads();
#pragma unroll
            for (int i = 0; i < 16; ++i) {
                const int chunk = i * 512 + tid;
                const int row = chunk >> 4, c16 = chunk & 15;
                const int p = row >> 6, chl = row & 63;
                const int wrp = p >> 2, wcp = p & 3;
                const uint4 v = *(const uint4*)(sm + p * 8704 + chl * 136 + c16 * 8);
                *(uint4*)(qkT + ((b * 2048 + n0 + wcp * 64 + chl) * 4096L + tok0 + wrp * 128 + c16 * 8)) = v;
            }
        } else {
            u16* piece = sm + wid * 8704;
#pragma unroll
            for (int mi = 0; mi < 8; ++mi)
#pragma unroll
                for (int ni = 0; ni < 4; ++ni) {
                    const int ch = ni * 16 + fr;
                    const int tk = mi * 16 + sl * 4;
#pragma unroll
                    for (int r = 0; r < 4; ++r)
                        piece[(tk + r) * 68 + ch] = f2bf(acc[mi][ni][r]);
                }
            __syncthreads();
#pragma unroll
            for (int i = 0; i < 32; ++i) {
                const int chunk = i * 512 + tid;
                const int row = chunk >> 4, c8 = chunk & 15;
                const int p = row >> 7, tk = row & 127;
                const int wrp = p >> 2, wcp = p & 3;
                const uint2 v = *(const uint2*)(sm + p * 8704 + tk * 68 + c8 * 4);
                *(uint2*)(v_tm + ((b * 4096 + tok0 + wrp * 128 + tk) * 1024L + (n0 - 2048) + wcp * 64 + c8 * 4)) = v;
            }
        }
    } else {
        float bi[4];
#pragma unroll
        for (int ni = 0; ni < 4; ++ni) bi[ni] = bias[n0 + wc * 64 + ni * 16 + fr];
#pragma unroll
        for (int pass = 0; pass < 2; ++pass) {
            float* pieceF = (float*)smem4 + wid * 4352;
            if (pass) __syncthreads();
#pragma unroll
            for (int mi2 = 0; mi2 < 4; ++mi2) {
                const int mi = pass * 4 + mi2;
#pragma unroll
                for (int ni = 0; ni < 4; ++ni) {
                    const int ch = ni * 16 + fr;
                    const int tk = mi2 * 16 + sl * 4;
#pragma unroll
                    for (int r = 0; r < 4; ++r)
                        pieceF[(tk + r) * 68 + ch] = acc[mi][ni][r] + bi[ni];
                }
            }
            __syncthreads();
#pragma unroll
            for (int i = 0; i < 16; ++i) {
                const int chunk = i * 512 + tid;
                const int row = chunk >> 4, c4 = chunk & 15;
                const int p = row >> 6, tk = row & 63;
                const int wrp = p >> 2, wcp = p & 3;
                const float4 v = *(const float4*)((float*)smem4 + p * 4352 + tk * 68 + c4 * 4);
                *(float4*)(outp + (m0 + wrp * 128 + pass * 64 + tk) * 1024L + n0 + wcp * 64 + c4 * 4) = v;
            }
        }
    }
}

// ---------------- partial Gram + partial square-sums per (b,h,seg) ----------------
// grid: (b*16+h)*16+seg, 512 threads. seg covers 256 tokens.
__global__ __launch_bounds__(512, 2) void k_gram(
    const u16* __restrict__ qkT, float* __restrict__ gram_part, float* __restrict__ sq_part)
{
    __shared__ u16 lQ[64 * 256];   // 32 KiB, rows of 512B, source-swizzled
    __shared__ u16 lK[64 * 256];   // 32 KiB

    const int blk = blockIdx.x;
    const int seg = blk & 15;
    const int bh = blk >> 4;
    const int b = bh >> 4, h = bh & 15;
    const int tid = threadIdx.x;
    const int wid = tid >> 6, lane = tid & 63;

    // stage: per wave 8 rows of q and k; each gload covers 2 rows (1KB)
    {
        const int r2 = lane >> 5;
        const int slot = lane & 31;
        const int rbase = wid * 8;
#pragma unroll
        for (int i = 0; i < 4; ++i) {
            const int r = rbase + i * 2 + r2;
            const int col = seg * 256 + ((slot ^ (r & 7)) << 3);
            const u16* gq = qkT + ((long)(b * 2048 + h * 64 + r)) * 4096 + col;
            const u16* gk = qkT + ((long)(b * 2048 + 1024 + h * 64 + r)) * 4096 + col;
            __builtin_amdgcn_global_load_lds((gp_t)gq, (lp_t)(lQ + (rbase + i * 2) * 256), 16, 0, 0);
            __builtin_amdgcn_global_load_lds((gp_t)gk, (lp_t)(lK + (rbase + i * 2) * 256), 16, 0, 0);
        }
    }
    __syncthreads();

    // partial square-sums: 128 rows (64 q + 64 k), 4 threads per row
    {
        const int row = tid >> 2, q4 = tid & 3;
        const u16* src = (row < 64 ? lQ + row * 256 : lK + (row - 64) * 256) + q4 * 64;
        float s = 0.f;
#pragma unroll
        for (int i = 0; i < 8; ++i) {
            uint4 v = *(const uint4*)(src + i * 8);
            float a0, a1;
            a0 = bf2f((u16)(v.x & 0xFFFF)); a1 = bf2f((u16)(v.x >> 16)); s += a0 * a0 + a1 * a1;
            a0 = bf2f((u16)(v.y & 0xFFFF)); a1 = bf2f((u16)(v.y >> 16)); s += a0 * a0 + a1 * a1;
            a0 = bf2f((u16)(v.z & 0xFFFF)); a1 = bf2f((u16)(v.z >> 16)); s += a0 * a0 + a1 * a1;
            a0 = bf2f((u16)(v.w & 0xFFFF)); a1 = bf2f((u16)(v.w >> 16)); s += a0 * a0 + a1 * a1;
        }
        s += __shfl_xor(s, 1);
        s += __shfl_xor(s, 2);
        if (q4 == 0) sq_part[(long)blk * 128 + row] = s;
    }

    // partial Gram: 64x64 over K=256, 8 waves x 2 frags
    const int mrow = wid >> 1, npair = wid & 1;
    const int fr = lane & 15, sl = lane >> 4;
    f32x4 acc[2];
    acc[0] = (f32x4){0.f, 0.f, 0.f, 0.f};
    acc[1] = (f32x4){0.f, 0.f, 0.f, 0.f};
#pragma unroll
    for (int ks = 0; ks < 8; ++ks) {
        const int ra = mrow * 16 + fr;
        const bf16x8 a = *(const bf16x8*)(lQ + ra * 256 + (((ks * 4 + sl) ^ (ra & 7)) << 3));
#pragma unroll
        for (int ni = 0; ni < 2; ++ni) {
            const int rb = npair * 32 + ni * 16 + fr;
            const bf16x8 bb = *(const bf16x8*)(lK + rb * 256 + (((ks * 4 + sl) ^ (rb & 7)) << 3));
            acc[ni] = __builtin_amdgcn_mfma_f32_16x16x32_bf16(a, bb, acc[ni], 0, 0, 0);
        }
    }
    float* gp = gram_part + (long)blk * 4096;
#pragma unroll
    for (int ni = 0; ni < 2; ++ni)
#pragma unroll
        for (int r = 0; r < 4; ++r)
            gp[(mrow * 16 + sl * 4 + r) * 64 + npair * 32 + ni * 16 + fr] = acc[ni][r];
}

// ---------------- reduce partials + normalize + softmax -> attn bf16 ----------------
// one wave per (b,h,d) row; grid 2048 x 256
__global__ __launch_bounds__(256) void k_smax(
    const float* __restrict__ gram_part, const float* __restrict__ sq_part,
    const float* __restrict__ temperature, u16* __restrict__ attn_g)
{
    const int row = blockIdx.x * 4 + (threadIdx.x >> 6);   // (b,h,d), 8192 total
    const int e = threadIdx.x & 63;
    const int bh = row >> 6, d = row & 63;
    const int h = bh & 15;
    float raw = 0.f, sqq = 0.f, sqk = 0.f;
    const float* gp = gram_part + (long)bh * 16 * 4096 + d * 64 + e;
    const float* sp = sq_part + (long)bh * 16 * 128;
#pragma unroll
    for (int s = 0; s < 16; ++s) {
        raw += gp[s * 4096];
        sqq += sp[s * 128 + d];
        sqk += sp[s * 128 + 64 + e];
    }
    const float rq = 1.f / fmaxf(sqrtf(sqq), 1e-12f);
    const float rk = 1.f / fmaxf(sqrtf(sqk), 1e-12f);
    const float v = raw * rq * rk * temperature[h];
    float mx = v;
#pragma unroll
    for (int o = 32; o; o >>= 1) mx = fmaxf(mx, __shfl_xor(mx, o));
    const float p = __expf(v - mx);
    float sum = p;
#pragma unroll
    for (int o = 32; o; o >>= 1) sum += __shfl_xor(sum, o);
    attn_g[(long)row * 64 + e] = f2bf(p / sum);
}

// ---------------- PV: y[b, n, h*64+d] = sum_e attn[d][e] * v[e][n] ----------------
__global__ __launch_bounds__(256) void k_pv(
    const u16* __restrict__ attn_g, const u16* __restrict__ v_tm,
    u16* __restrict__ y)
{
    __shared__ u16 lP[64 * 72];
    __shared__ u16 lV[128 * 64];
    __shared__ u16 lY[128 * 72];

    const int blk = blockIdx.x;
    const int seg = blk & 15, bh = blk >> 4;
    const int b = bh >> 4, h = bh & 15;
    const int tid = threadIdx.x;
    const int wid = tid >> 6, lane = tid & 63;
    const int wr = wid >> 1, wc = wid & 1;
    const int fr = lane & 15;

    {
        const int d = tid >> 2, part = tid & 3;
        const u16* g = attn_g + ((long)bh * 64 + d) * 64 + part * 16;
        u16* l = lP + d * 72 + part * 16;
        *(uint4*)(l) = *(const uint4*)(g);
        *(uint4*)(l + 8) = *(const uint4*)(g + 8);
    }

    for (int cn = 0; cn < 2; ++cn) {
        const int tok0 = seg * 256 + cn * 128;
        __syncthreads();
#pragma unroll
        for (int i = 0; i < 4; ++i) {
            const int cc = wid * 4 + i;
            const int row = cc * 8 + (lane >> 3);
            const int slot = lane & 7;
            const u16* g = v_tm + ((long)(b * 4096 + tok0 + row)) * 1024 + h * 64 + ((slot ^ (row & 7)) << 3);
            __builtin_amdgcn_global_load_lds((gp_t)g, (lp_t)(lV + cc * 512), 16, 0, 0);
        }
        __syncthreads();
        f32x4 acc[2][4];
#pragma unroll
        for (int i = 0; i < 2; ++i)
#pragma unroll
            for (int j = 0; j < 4; ++j) acc[i][j] = (f32x4){0.f, 0.f, 0.f, 0.f};
#pragma unroll
        for (int s = 0; s < 2; ++s) {
            bf16x8 ap[2];
#pragma unroll
            for (int mi = 0; mi < 2; ++mi) {
                const int d = wr * 32 + mi * 16 + fr;
                ap[mi] = *(const bf16x8*)(lP + d * 72 + s * 32 + ((lane >> 4) << 3));
            }
#pragma unroll
            for (int ni = 0; ni < 4; ++ni) {
                const int tr = wc * 64 + ni * 16 + fr;
                const bf16x8 bv = *(const bf16x8*)(lV + tr * 64 + (((s * 4 + (lane >> 4)) ^ (tr & 7)) << 3));
#pragma unroll
                for (int mi = 0; mi < 2; ++mi)
                    acc[mi][ni] = __builtin_amdgcn_mfma_f32_16x16x32_bf16(ap[mi], bv, acc[mi][ni], 0, 0, 0);
            }
        }
#pragma unroll
        for (int mi = 0; mi < 2; ++mi)
#pragma unroll
            for (int ni = 0; ni < 4; ++ni) {
                const int tk = wc * 64 + ni * 16 + fr;
                const int d0 = wr * 32 + mi * 16 + ((lane >> 4) << 2);
                ushort4 w;
                w.x = f2bf(acc[mi][ni][0]); w.y = f2bf(acc[mi][ni][1]);
                w.z = f2bf(acc[mi][ni][2]); w.w = f2bf(acc[mi][ni][3]);
                *(ushort4*)(lY + tk * 72 + d0) = w;
            }
        __syncthreads();
        {
            const int tk = tid >> 1, half = tid & 1;
            const u16* sp = lY + tk * 72 + half * 32;
            u16* dp = y + ((long)(b * 4096 + tok0 + tk)) * 1024 + h * 64 + half * 32;
#pragma unroll
            for (int i = 0; i < 4; ++i)
                ((uint4*)dp)[i] = ((const uint4*)sp)[i];
        }
    }
}

// ---------------- launch ----------------
extern "C" void kernel_launch(void* const* d_in, const int* in_sizes, int n_in,
                              void* d_out, int out_size, void* d_ws, size_t ws_size,
                              hipStream_t stream) {
    const float* x = (const float*)d_in[0];
    const float* w_qkv = (const float*)d_in[1];
    const float* temperature = (const float*)d_in[2];
    const float* w_proj = (const float*)d_in[3];
    const float* b_proj = (const float*)d_in[4];
    float* out = (float*)d_out;
    char* ws = (char*)d_ws;

    u16* wqT   = (u16*)(ws);                       //   6,291,456 B  [3072][1024] bf16
    u16* wpT   = (u16*)(ws + 6291456);             //   2,097,152 B  [1024][1024] bf16
    u16* xb    = (u16*)(ws + 8388608);             //  67,108,864 B  [32768][1024] bf16
    u16* qkT   = (u16*)(ws + 75497472);            // 134,217,728 B  [8][2048][4096] bf16
    u16* v_tm  = (u16*)(ws + 209715200);           //  67,108,864 B  [8][4096][1024] bf16
    u16* attn_g = (u16*)(ws + 276889600);          //   1,048,576 B  [128][64][64] bf16
    // overlays on the xb region (xb dead after GEMM1; y written only after k_smax):
    float* gram_part = (float*)(ws + 8388608);     //  33,554,432 B  [2048][64][64] f32
    float* sq_part   = (float*)(ws + 41943040);    //   1,048,576 B  [2048][128] f32
    u16* y = xb;                                   // alias: written by k_pv after k_smax

    k_pack_x<<<2048, 256, 0, stream>>>(x, xb, 8388608);
    k_transpose_w<<<768, 256, 0, stream>>>(w_qkv, wqT, 3072);
    k_transpose_w<<<256, 256, 0, stream>>>(w_proj, wpT, 1024);
    k_gemm<0><<<1536, 512, 0, stream>>>(xb, wqT, 12, qkT, v_tm, nullptr, nullptr);
    k_gram<<<2048, 512, 0, stream>>>(qkT, gram_part, sq_part);
    k_smax<<<2048, 256, 0, stream>>>(gram_part, sq_part, temperature, attn_g);
    k_pv<<<2048, 256, 0, stream>>>(attn_g, v_tm, y);
    k_gemm<1><<<512, 512, 0, stream>>>(y, wpT, 4, nullptr, nullptr, out, b_proj);
}

// Round 4
// 411.449 us; speedup vs baseline: 1.3222x; 1.0126x over previous
//
#include <hip/hip_runtime.h>
#include <cstdint>

typedef unsigned short u16;
typedef unsigned int u32;
typedef __attribute__((ext_vector_type(8))) short bf16x8;
typedef __attribute__((ext_vector_type(4))) float f32x4;

typedef const u32 __attribute__((address_space(1)))* gp_t;
typedef u32 __attribute__((address_space(3)))* lp_t;

__device__ __forceinline__ u16 f2bf(float f) {
    union { float f; u32 u; } v; v.f = f;
    u32 r = v.u + 0x7FFFu + ((v.u >> 16) & 1u);   // RNE
    return (u16)(r >> 16);
}
__device__ __forceinline__ float bf2f(u16 h) {
    union { u32 u; float f; } v; v.u = ((u32)h) << 16;
    return v.f;
}

// ---------------- pack x (fp32 -> bf16), vectorized ----------------
__global__ void k_pack_x(const float* __restrict__ x, u16* __restrict__ xb, int n4) {
    int stride = gridDim.x * blockDim.x;
    for (int i = blockIdx.x * blockDim.x + threadIdx.x; i < n4; i += stride) {
        float4 v = ((const float4*)x)[i];
        ushort4 o;
        o.x = f2bf(v.x); o.y = f2bf(v.y); o.z = f2bf(v.z); o.w = f2bf(v.w);
        ((ushort4*)xb)[i] = o;
    }
}

// ---------------- transpose weight [1024][ncols] f32 -> [ncols][1024] bf16 ----
__global__ void k_transpose_w(const float* __restrict__ src, u16* __restrict__ dst, int ncols) {
    __shared__ float t[64][65];
    int ntn = ncols >> 6;
    int kb = (blockIdx.x / ntn) * 64;
    int nb = (blockIdx.x % ntn) * 64;
    for (int i = threadIdx.x; i < 4096; i += 256) {
        int r = i >> 6, c = i & 63;
        t[r][c] = src[(long)(kb + r) * ncols + nb + c];
    }
    __syncthreads();
    for (int i = threadIdx.x; i < 4096; i += 256) {
        int r = i >> 6, c = i & 63;
        dst[(long)(nb + r) * 1024 + kb + c] = f2bf(t[c][r]);
    }
}

// ---------------- 256x256 GEMM, BK=64, 8-phase (2 K-tiles/iter pattern) ----------
// LDS elems (u16): A: [d][kh][256r][32k] d-stride 16384, kh-stride 8192
//                  B: same at +32768. Total 131072 B.
// Per K-tile(64): 4 phases = (ks,mh) quadrants, 16 MFMA each.
// Stage exactly 1 half-tile (matrix x k-half, 16KB) per phase; vmcnt(8) at P2,P4.
template<int EPI>
__global__ __launch_bounds__(512, 2) void k_gemm(
    const u16* __restrict__ A, const u16* __restrict__ Bt,
    int nTilesN,
    u16* __restrict__ qkT, u16* __restrict__ v_tm,
    float* __restrict__ outp, const float* __restrict__ bias)
{
    __shared__ uint4 smem4[8704];            // 139264 B (main loop uses first 128 KiB)
    u16* sm = (u16*)smem4;

    const int tid = threadIdx.x;
    const int wid = tid >> 6, lane = tid & 63;
    const int wr = wid >> 2, wc = wid & 3;   // 2M x 4N waves
    const int fr = lane & 15, sl = lane >> 4;

    const int nwg = gridDim.x;
    const int cpx = nwg >> 3;
    const int logical = (blockIdx.x & 7) * cpx + (blockIdx.x >> 3);
    const int bn = logical % nTilesN;
    const long bm = logical / nTilesN;
    const long m0 = bm * 256;
    const int n0 = bn * 256;

    // staging geometry: per stage-call a wave writes 2x1KB linear chunks (16 rows x 64B)
    const int srow = wid * 32 + (lane >> 2);            // row for chunk j=0 (j=1: +16, same swz)
    const int kswz = (((lane & 3) ^ ((srow >> 1) & 3)) << 3);   // swizzled k-elem offset
    const u16* gA = A + (m0 + srow) * 1024L + kswz;
    const u16* gB = Bt + ((long)n0 + srow) * 1024L + kswz;
    const int ldst = wid * 1024;                        // elems, + lane*16B implied by HW

    // frag-read geometry (XOR slot is row-invariant per lane: (fr>>1)&3)
    const int fxor = ((sl ^ ((fr >> 1) & 3)) << 3);
    const int aBase = (wr * 128 + fr) * 32 + fxor;      // + mi*512 + d*16384 + ks*8192
    const int bBase = 32768 + (wc * 64 + fr) * 32 + fxor;

    f32x4 acc[8][4];
#pragma unroll
    for (int i = 0; i < 8; ++i)
#pragma unroll
        for (int j = 0; j < 4; ++j) acc[i][j] = (f32x4){0.f, 0.f, 0.f, 0.f};

#define STAGE_A(d, kh, ts) do { \
    const u16* g_ = gA + (ts) * 64 + (kh) * 32; \
    u16* l_ = sm + (d) * 16384 + (kh) * 8192 + ldst; \
    __builtin_amdgcn_global_load_lds((gp_t)g_, (lp_t)l_, 16, 0, 0); \
    __builtin_amdgcn_global_load_lds((gp_t)(g_ + 16 * 1024), (lp_t)(l_ + 512), 16, 0, 0); \
} while (0)
#define STAGE_B(d, kh, ts) do { \
    const u16* g_ = gB + (ts) * 64 + (kh) * 32; \
    u16* l_ = sm + 32768 + (d) * 16384 + (kh) * 8192 + ldst; \
    __builtin_amdgcn_global_load_lds((gp_t)g_, (lp_t)l_, 16, 0, 0); \
    __builtin_amdgcn_global_load_lds((gp_t)(g_ + 16 * 1024), (lp_t)(l_ + 512), 16, 0, 0); \
} while (0)

    // prologue: T0.A.kh0, T0.B.kh0, T0.A.kh1, T0.B.kh1, T1.A.kh0, T1.B.kh0
    STAGE_A(0, 0, 0); STAGE_B(0, 0, 0);
    STAGE_A(0, 1, 0); STAGE_B(0, 1, 0);
    STAGE_A(1, 0, 1); STAGE_B(1, 0, 1);
    asm volatile("s_waitcnt vmcnt(8)" ::: "memory");   // T0.kh0 landed
    __builtin_amdgcn_s_barrier();

    bf16x8 bfr[4], af[4];
#pragma unroll 2
    for (int T = 0; T < 16; ++T) {
        const int d = T & 1;
        const int t1 = (T + 1 < 16) ? T + 1 : 15;
        const int t2 = (T + 2 < 16) ? T + 2 : 15;
        const int base = d * 16384;

        // ---- P1: ks0, m-half0 ----
#pragma unroll
        for (int ni = 0; ni < 4; ++ni)
            bfr[ni] = *(const bf16x8*)(sm + bBase + ni * 512 + base);
#pragma unroll
        for (int mi = 0; mi < 4; ++mi)
            af[mi] = *(const bf16x8*)(sm + aBase + mi * 512 + base);
        STAGE_A(d ^ 1, 1, t1);                          // (T+1).A.kh1
        __builtin_amdgcn_s_barrier();
        __builtin_amdgcn_s_setprio(1);
#pragma unroll
        for (int mi = 0; mi < 4; ++mi)
#pragma unroll
            for (int ni = 0; ni < 4; ++ni)
                acc[mi][ni] = __builtin_amdgcn_mfma_f32_16x16x32_bf16(af[mi], bfr[ni], acc[mi][ni], 0, 0, 0);
        __builtin_amdgcn_s_setprio(0);
        __builtin_amdgcn_s_barrier();

        // ---- P2: ks0, m-half1 ----
#pragma unroll
        for (int mi = 0; mi < 4; ++mi)
            af[mi] = *(const bf16x8*)(sm + aBase + (4 + mi) * 512 + base);
        STAGE_B(d ^ 1, 1, t1);                          // (T+1).B.kh1
        asm volatile("s_waitcnt vmcnt(8)" ::: "memory");// T.kh1 (A,B) landed
        __builtin_amdgcn_s_barrier();
        __builtin_amdgcn_s_setprio(1);
#pragma unroll
        for (int mi = 0; mi < 4; ++mi)
#pragma unroll
            for (int ni = 0; ni < 4; ++ni)
                acc[mi + 4][ni] = __builtin_amdgcn_mfma_f32_16x16x32_bf16(af[mi], bfr[ni], acc[mi + 4][ni], 0, 0, 0);
        __builtin_amdgcn_s_setprio(0);
        __builtin_amdgcn_s_barrier();

        // ---- P3: ks1, m-half0 ----
#pragma unroll
        for (int ni = 0; ni < 4; ++ni)
            bfr[ni] = *(const bf16x8*)(sm + bBase + ni * 512 + base + 8192);
#pragma unroll
        for (int mi = 0; mi < 4; ++mi)
            af[mi] = *(const bf16x8*)(sm + aBase + mi * 512 + base + 8192);
        STAGE_A(d, 0, t2);                              // (T+2).A.kh0
        __builtin_amdgcn_s_barrier();
        __builtin_amdgcn_s_setprio(1);
#pragma unroll
        for (int mi = 0; mi < 4; ++mi)
#pragma unroll
            for (int ni = 0; ni < 4; ++ni)
                acc[mi][ni] = __builtin_amdgcn_mfma_f32_16x16x32_bf16(af[mi], bfr[ni], acc[mi][ni], 0, 0, 0);
        __builtin_amdgcn_s_setprio(0);
        __builtin_amdgcn_s_barrier();

        // ---- P4: ks1, m-half1 ----
#pragma unroll
        for (int mi = 0; mi < 4; ++mi)
            af[mi] = *(const bf16x8*)(sm + aBase + (4 + mi) * 512 + base + 8192);
        STAGE_B(d, 0, t2);                              // (T+2).B.kh0
        asm volatile("s_waitcnt vmcnt(8)" ::: "memory");// (T+1).kh0 (A,B) landed
        __builtin_amdgcn_s_barrier();
        __builtin_amdgcn_s_setprio(1);
#pragma unroll
        for (int mi = 0; mi < 4; ++mi)
#pragma unroll
            for (int ni = 0; ni < 4; ++ni)
                acc[mi + 4][ni] = __builtin_amdgcn_mfma_f32_16x16x32_bf16(af[mi], bfr[ni], acc[mi + 4][ni], 0, 0, 0);
        __builtin_amdgcn_s_setprio(0);
        __builtin_amdgcn_s_barrier();
    }
#undef STAGE_A
#undef STAGE_B
    asm volatile("s_waitcnt vmcnt(0)" ::: "memory");   // drain tail junk stages
    __syncthreads();

    if (EPI == 0) {
        const long b = m0 >> 12;
        const int tok0 = (int)(m0 & 4095);
        if (n0 < 2048) {
            u16* piece = sm + wid * 8704;
#pragma unroll
            for (int mi = 0; mi < 8; ++mi)
#pragma unroll
                for (int ni = 0; ni < 4; ++ni) {
                    const int ch = ni * 16 + fr;
                    const int tk = mi * 16 + sl * 4;
                    ushort4 w;
                    w.x = f2bf(acc[mi][ni][0]); w.y = f2bf(acc[mi][ni][1]);
                    w.z = f2bf(acc[mi][ni][2]); w.w = f2bf(acc[mi][ni][3]);
                    *(ushort4*)(piece + ch * 136 + tk) = w;
                }
            __syncthreads();
#pragma unroll
            for (int i = 0; i < 16; ++i) {
                const int chunk = i * 512 + tid;
                const int row = chunk >> 4, c16 = chunk & 15;
                const int p = row >> 6, chl = row & 63;
                const int wrp = p >> 2, wcp = p & 3;
                const uint4 v = *(const uint4*)(sm + p * 8704 + chl * 136 + c16 * 8);
                *(uint4*)(qkT + ((b * 2048 + n0 + wcp * 64 + chl) * 4096L + tok0 + wrp * 128 + c16 * 8)) = v;
            }
        } else {
            u16* piece = sm + wid * 8704;
#pragma unroll
            for (int mi = 0; mi < 8; ++mi)
#pragma unroll
                for (int ni = 0; ni < 4; ++ni) {
                    const int ch = ni * 16 + fr;
                    const int tk = mi * 16 + sl * 4;
#pragma unroll
                    for (int r = 0; r < 4; ++r)
                        piece[(tk + r) * 68 + ch] = f2bf(acc[mi][ni][r]);
                }
            __syncthreads();
#pragma unroll
            for (int i = 0; i < 32; ++i) {
                const int chunk = i * 512 + tid;
                const int row = chunk >> 4, c8 = chunk & 15;
                const int p = row >> 7, tk = row & 127;
                const int wrp = p >> 2, wcp = p & 3;
                const uint2 v = *(const uint2*)(sm + p * 8704 + tk * 68 + c8 * 4);
                *(uint2*)(v_tm + ((b * 4096 + tok0 + wrp * 128 + tk) * 1024L + (n0 - 2048) + wcp * 64 + c8 * 4)) = v;
            }
        }
    } else {
        float bi[4];
#pragma unroll
        for (int ni = 0; ni < 4; ++ni) bi[ni] = bias[n0 + wc * 64 + ni * 16 + fr];
#pragma unroll
        for (int pass = 0; pass < 2; ++pass) {
            float* pieceF = (float*)smem4 + wid * 4352;
            if (pass) __syncthreads();
#pragma unroll
            for (int mi2 = 0; mi2 < 4; ++mi2) {
                const int mi = pass * 4 + mi2;
#pragma unroll
                for (int ni = 0; ni < 4; ++ni) {
                    const int ch = ni * 16 + fr;
                    const int tk = mi2 * 16 + sl * 4;
#pragma unroll
                    for (int r = 0; r < 4; ++r)
                        pieceF[(tk + r) * 68 + ch] = acc[mi][ni][r] + bi[ni];
                }
            }
            __syncthreads();
#pragma unroll
            for (int i = 0; i < 16; ++i) {
                const int chunk = i * 512 + tid;
                const int row = chunk >> 4, c4 = chunk & 15;
                const int p = row >> 6, tk = row & 63;
                const int wrp = p >> 2, wcp = p & 3;
                const float4 v = *(const float4*)((float*)smem4 + p * 4352 + tk * 68 + c4 * 4);
                *(float4*)(outp + (m0 + wrp * 128 + pass * 64 + tk) * 1024L + n0 + wcp * 64 + c4 * 4) = v;
            }
        }
    }
}

// ---------------- partial Gram + partial square-sums per (b,h,seg) ----------------
__global__ __launch_bounds__(512, 2) void k_gram(
    const u16* __restrict__ qkT, float* __restrict__ gram_part, float* __restrict__ sq_part)
{
    __shared__ u16 lQ[64 * 256];
    __shared__ u16 lK[64 * 256];

    const int blk = blockIdx.x;
    const int seg = blk & 15;
    const int bh = blk >> 4;
    const int b = bh >> 4, h = bh & 15;
    const int tid = threadIdx.x;
    const int wid = tid >> 6, lane = tid & 63;

    {
        const int r2 = lane >> 5;
        const int slot = lane & 31;
        const int rbase = wid * 8;
#pragma unroll
        for (int i = 0; i < 4; ++i) {
            const int r = rbase + i * 2 + r2;
            const int col = seg * 256 + ((slot ^ (r & 7)) << 3);
            const u16* gq = qkT + ((long)(b * 2048 + h * 64 + r)) * 4096 + col;
            const u16* gk = qkT + ((long)(b * 2048 + 1024 + h * 64 + r)) * 4096 + col;
            __builtin_amdgcn_global_load_lds((gp_t)gq, (lp_t)(lQ + (rbase + i * 2) * 256), 16, 0, 0);
            __builtin_amdgcn_global_load_lds((gp_t)gk, (lp_t)(lK + (rbase + i * 2) * 256), 16, 0, 0);
        }
    }
    __syncthreads();

    {
        const int row = tid >> 2, q4 = tid & 3;
        const u16* src = (row < 64 ? lQ + row * 256 : lK + (row - 64) * 256) + q4 * 64;
        float s = 0.f;
#pragma unroll
        for (int i = 0; i < 8; ++i) {
            uint4 v = *(const uint4*)(src + i * 8);
            float a0, a1;
            a0 = bf2f((u16)(v.x & 0xFFFF)); a1 = bf2f((u16)(v.x >> 16)); s += a0 * a0 + a1 * a1;
            a0 = bf2f((u16)(v.y & 0xFFFF)); a1 = bf2f((u16)(v.y >> 16)); s += a0 * a0 + a1 * a1;
            a0 = bf2f((u16)(v.z & 0xFFFF)); a1 = bf2f((u16)(v.z >> 16)); s += a0 * a0 + a1 * a1;
            a0 = bf2f((u16)(v.w & 0xFFFF)); a1 = bf2f((u16)(v.w >> 16)); s += a0 * a0 + a1 * a1;
        }
        s += __shfl_xor(s, 1);
        s += __shfl_xor(s, 2);
        if (q4 == 0) sq_part[(long)blk * 128 + row] = s;
    }

    const int mrow = wid >> 1, npair = wid & 1;
    const int fr = lane & 15, sl = lane >> 4;
    f32x4 acc[2];
    acc[0] = (f32x4){0.f, 0.f, 0.f, 0.f};
    acc[1] = (f32x4){0.f, 0.f, 0.f, 0.f};
#pragma unroll
    for (int ks = 0; ks < 8; ++ks) {
        const int ra = mrow * 16 + fr;
        const bf16x8 a = *(const bf16x8*)(lQ + ra * 256 + (((ks * 4 + sl) ^ (ra & 7)) << 3));
#pragma unroll
        for (int ni = 0; ni < 2; ++ni) {
            const int rb = npair * 32 + ni * 16 + fr;
            const bf16x8 bb = *(const bf16x8*)(lK + rb * 256 + (((ks * 4 + sl) ^ (rb & 7)) << 3));
            acc[ni] = __builtin_amdgcn_mfma_f32_16x16x32_bf16(a, bb, acc[ni], 0, 0, 0);
        }
    }
    float* gp = gram_part + (long)blk * 4096;
#pragma unroll
    for (int ni = 0; ni < 2; ++ni)
#pragma unroll
        for (int r = 0; r < 4; ++r)
            gp[(mrow * 16 + sl * 4 + r) * 64 + npair * 32 + ni * 16 + fr] = acc[ni][r];
}

// ---------------- reduce partials + normalize + softmax -> attn bf16 ----------------
__global__ __launch_bounds__(256) void k_smax(
    const float* __restrict__ gram_part, const float* __restrict__ sq_part,
    const float* __restrict__ temperature, u16* __restrict__ attn_g)
{
    const int row = blockIdx.x * 4 + (threadIdx.x >> 6);
    const int e = threadIdx.x & 63;
    const int bh = row >> 6, d = row & 63;
    const int h = bh & 15;
    float raw = 0.f, sqq = 0.f, sqk = 0.f;
    const float* gp = gram_part + (long)bh * 16 * 4096 + d * 64 + e;
    const float* sp = sq_part + (long)bh * 16 * 128;
#pragma unroll
    for (int s = 0; s < 16; ++s) {
        raw += gp[s * 4096];
        sqq += sp[s * 128 + d];
        sqk += sp[s * 128 + 64 + e];
    }
    const float rq = 1.f / fmaxf(sqrtf(sqq), 1e-12f);
    const float rk = 1.f / fmaxf(sqrtf(sqk), 1e-12f);
    const float v = raw * rq * rk * temperature[h];
    float mx = v;
#pragma unroll
    for (int o = 32; o; o >>= 1) mx = fmaxf(mx, __shfl_xor(mx, o));
    const float p = __expf(v - mx);
    float sum = p;
#pragma unroll
    for (int o = 32; o; o >>= 1) sum += __shfl_xor(sum, o);
    attn_g[(long)row * 64 + e] = f2bf(p / sum);
}

// ---------------- PV: y[b, n, h*64+d] = sum_e attn[d][e] * v[e][n] ----------------
__global__ __launch_bounds__(256) void k_pv(
    const u16* __restrict__ attn_g, const u16* __restrict__ v_tm,
    u16* __restrict__ y)
{
    __shared__ u16 lP[64 * 72];
    __shared__ u16 lV[128 * 64];
    __shared__ u16 lY[128 * 72];

    const int blk = blockIdx.x;
    const int seg = blk & 15, bh = blk >> 4;
    const int b = bh >> 4, h = bh & 15;
    const int tid = threadIdx.x;
    const int wid = tid >> 6, lane = tid & 63;
    const int wr = wid >> 1, wc = wid & 1;
    const int fr = lane & 15;

    {
        const int d = tid >> 2, part = tid & 3;
        const u16* g = attn_g + ((long)bh * 64 + d) * 64 + part * 16;
        u16* l = lP + d * 72 + part * 16;
        *(uint4*)(l) = *(const uint4*)(g);
        *(uint4*)(l + 8) = *(const uint4*)(g + 8);
    }

    for (int cn = 0; cn < 2; ++cn) {
        const int tok0 = seg * 256 + cn * 128;
        __syncthreads();
#pragma unroll
        for (int i = 0; i < 4; ++i) {
            const int cc = wid * 4 + i;
            const int row = cc * 8 + (lane >> 3);
            const int slot = lane & 7;
            const u16* g = v_tm + ((long)(b * 4096 + tok0 + row)) * 1024 + h * 64 + ((slot ^ (row & 7)) << 3);
            __builtin_amdgcn_global_load_lds((gp_t)g, (lp_t)(lV + cc * 512), 16, 0, 0);
        }
        __syncthreads();
        f32x4 acc[2][4];
#pragma unroll
        for (int i = 0; i < 2; ++i)
#pragma unroll
            for (int j = 0; j < 4; ++j) acc[i][j] = (f32x4){0.f, 0.f, 0.f, 0.f};
#pragma unroll
        for (int s = 0; s < 2; ++s) {
            bf16x8 ap[2];
#pragma unroll
            for (int mi = 0; mi < 2; ++mi) {
                const int d = wr * 32 + mi * 16 + fr;
                ap[mi] = *(const bf16x8*)(lP + d * 72 + s * 32 + ((lane >> 4) << 3));
            }
#pragma unroll
            for (int ni = 0; ni < 4; ++ni) {
                const int tr = wc * 64 + ni * 16 + fr;
                const bf16x8 bv = *(const bf16x8*)(lV + tr * 64 + (((s * 4 + (lane >> 4)) ^ (tr & 7)) << 3));
#pragma unroll
                for (int mi = 0; mi < 2; ++mi)
                    acc[mi][ni] = __builtin_amdgcn_mfma_f32_16x16x32_bf16(ap[mi], bv, acc[mi][ni], 0, 0, 0);
            }
        }
#pragma unroll
        for (int mi = 0; mi < 2; ++mi)
#pragma unroll
            for (int ni = 0; ni < 4; ++ni) {
                const int tk = wc * 64 + ni * 16 + fr;
                const int d0 = wr * 32 + mi * 16 + ((lane >> 4) << 2);
                ushort4 w;
                w.x = f2bf(acc[mi][ni][0]); w.y = f2bf(acc[mi][ni][1]);
                w.z = f2bf(acc[mi][ni][2]); w.w = f2bf(acc[mi][ni][3]);
                *(ushort4*)(lY + tk * 72 + d0) = w;
            }
        __syncthreads();
        {
            const int tk = tid >> 1, half = tid & 1;
            const u16* sp = lY + tk * 72 + half * 32;
            u16* dp = y + ((long)(b * 4096 + tok0 + tk)) * 1024 + h * 64 + half * 32;
#pragma unroll
            for (int i = 0; i < 4; ++i)
                ((uint4*)dp)[i] = ((const uint4*)sp)[i];
        }
    }
}

// ---------------- launch ----------------
extern "C" void kernel_launch(void* const* d_in, const int* in_sizes, int n_in,
                              void* d_out, int out_size, void* d_ws, size_t ws_size,
                              hipStream_t stream) {
    const float* x = (const float*)d_in[0];
    const float* w_qkv = (const float*)d_in[1];
    const float* temperature = (const float*)d_in[2];
    const float* w_proj = (const float*)d_in[3];
    const float* b_proj = (const float*)d_in[4];
    float* out = (float*)d_out;
    char* ws = (char*)d_ws;

    u16* wqT   = (u16*)(ws);                       //   6,291,456 B  [3072][1024] bf16
    u16* wpT   = (u16*)(ws + 6291456);             //   2,097,152 B  [1024][1024] bf16
    u16* xb    = (u16*)(ws + 8388608);             //  67,108,864 B  [32768][1024] bf16
    u16* qkT   = (u16*)(ws + 75497472);            // 134,217,728 B  [8][2048][4096] bf16
    u16* v_tm  = (u16*)(ws + 209715200);           //  67,108,864 B  [8][4096][1024] bf16
    u16* attn_g = (u16*)(ws + 276889600);          //   1,048,576 B  [128][64][64] bf16
    float* gram_part = (float*)(ws + 8388608);     //  33,554,432 B  [2048][64][64] f32 (xb overlay)
    float* sq_part   = (float*)(ws + 41943040);    //   1,048,576 B  [2048][128] f32
    u16* y = xb;                                   // alias: written by k_pv after k_smax

    k_pack_x<<<2048, 256, 0, stream>>>(x, xb, 8388608);
    k_transpose_w<<<768, 256, 0, stream>>>(w_qkv, wqT, 3072);
    k_transpose_w<<<256, 256, 0, stream>>>(w_proj, wpT, 1024);
    k_gemm<0><<<1536, 512, 0, stream>>>(xb, wqT, 12, qkT, v_tm, nullptr, nullptr);
    k_gram<<<2048, 512, 0, stream>>>(qkT, gram_part, sq_part);
    k_smax<<<2048, 256, 0, stream>>>(gram_part, sq_part, temperature, attn_g);
    k_pv<<<2048, 256, 0, stream>>>(attn_g, v_tm, y);
    k_gemm<1><<<512, 512, 0, stream>>>(y, wpT, 4, nullptr, nullptr, out, b_proj);
}